// Round 8
// baseline (357.868 us; speedup 1.0000x reference)
//
#include <hip/hip_runtime.h>

// GCN 2-layer: h = relu(Ahat @ (x @ W) + b), twice.
// Round 16: CSR finalize deleted. hs is pre-scaled by dinv in the GEMM
// epilogue (dinv = rsqrt(deg+1), deg from a cheap atomic histogram), so the
// gather needs NO per-src dinv and aggregation is a plain sum of hs' rows.
// Each aggregate block owns a 64-node half-bucket: reads its ebuf segment,
// counting-sorts it in LDS (hidden under gather latency), gathers via
// LDS-resident indices. fill2 / row_ptr / col (12.8 MB round-trip) deleted.
// Chain: memset -> k_deg -> fusedA(bsort||gemm1*dinv) -> aggB1(sort+gather+
// gemm2*dinv -> hs2') -> aggB2(sort+gather -> out).

#define NFEAT 128
#define BSH 7                  // 128 nodes per bucket
#define MAXNB 1024             // >= NB = ceil(N/128) = 782
#define BCAP 4096              // per-bucket ebuf capacity (mean 2046, sigma 45)
#define HP 72                  // ushorts per Bs row (64 k + 8 pad); word-stride 36 == 4 mod 32
#define YP 132                 // ushorts per yT row (128 + 4)
#define CH2 2048               // edges per bsort chunk
#define CLCAP 2064             // colL ints per half-bucket (2048 cap + prefetch pad)

typedef __attribute__((ext_vector_type(8))) short s8v;  // 8 bf16 MFMA A/B frag
typedef __attribute__((ext_vector_type(4))) float f4v;  // MFMA C/D frag
typedef __attribute__((ext_vector_type(2))) float f2v;  // packed f32 pair
typedef __attribute__((ext_vector_type(4))) uint u4v;   // NT-store vector

// ---- bf16 helpers (rne) ----
__device__ inline ushort f2bf(float f) {
    union { float f; uint u; } x; x.f = f;
    uint u = x.u;
    return (ushort)((u + 0x7fffu + ((u >> 16) & 1u)) >> 16);
}
__device__ inline f2v unpk(uint u) {
    union { uint u; float f; } lo, hi;
    lo.u = u << 16;
    hi.u = u & 0xffff0000u;
    return (f2v){lo.f, hi.f};
}
__device__ inline void upadd2(uint4 v, f2v* a) {
    a[0] += unpk(v.x);
    a[1] += unpk(v.y);
    a[2] += unpk(v.z);
    a[3] += unpk(v.w);
}

// ---- per-node gather from LDS index list: a[4] += hs'[c] rows, 4-deep pipeline ----
__device__ inline void node_gather_lds(const uint4* __restrict__ hs4,
                                       const int* colL, int s, int e,
                                       int node, int sub, f2v* a) {
    uint4 vself = hs4[(size_t)node * 16 + sub];
    int nb = (e - s) >> 2;
    int k = s;
    if (nb > 0) {
        int c0 = colL[k], c1 = colL[k + 1], c2 = colL[k + 2], c3 = colL[k + 3];
        uint4 v0 = hs4[(size_t)c0 * 16 + sub];
        uint4 v1 = hs4[(size_t)c1 * 16 + sub];
        uint4 v2 = hs4[(size_t)c2 * 16 + sub];
        uint4 v3 = hs4[(size_t)c3 * 16 + sub];
        int d0 = colL[k + 4], d1 = colL[k + 5], d2 = colL[k + 6], d3 = colL[k + 7];
        k += 8;
        upadd2(vself, a);  // self-loop FIRST
        for (int it = 1; it < nb; ++it, k += 4) {
            uint4 w0 = hs4[(size_t)d0 * 16 + sub];
            uint4 w1 = hs4[(size_t)d1 * 16 + sub];
            uint4 w2 = hs4[(size_t)d2 * 16 + sub];
            uint4 w3 = hs4[(size_t)d3 * 16 + sub];
            int t0 = colL[k], t1 = colL[k + 1], t2 = colL[k + 2], t3 = colL[k + 3];
            upadd2(v0, a); upadd2(v1, a); upadd2(v2, a); upadd2(v3, a);
            v0 = w0; v1 = w1; v2 = w2; v3 = w3;
            d0 = t0; d1 = t1; d2 = t2; d3 = t3;
        }
        upadd2(v0, a); upadd2(v1, a); upadd2(v2, a); upadd2(v3, a);
        k = s + nb * 4;
    } else {
        upadd2(vself, a);
    }
    for (; k < e; ++k) upadd2(hs4[(size_t)colL[k] * 16 + sub], a);
}

// ---- half-bucket counting sort: ebuf segment -> colL (LDS), cnt/sstart per node ----
// cnt/sstart indexed by local node 0..63 (within this half); pre is scratch.
__device__ inline void half_sort(const uint* __restrict__ ebuf,
                                 const int* __restrict__ gcnt,
                                 int b, int half, int* cnt, int* sstart, int* pre,
                                 int* colL) {
    int t = threadIdx.x;
    int m = min(gcnt[b], BCAP);
    const uint* eb = ebuf + (size_t)b * BCAP;
    if (t < 64) cnt[t] = 0;
    __syncthreads();
    for (int i = t; i < m; i += 256) {
        int low = (int)(eb[i] & 127u);
        if ((low >> 6) == half) atomicAdd(&cnt[low & 63], 1);
    }
    __syncthreads();
    if (t < 64) {
        int v = cnt[t];
        int sc = v;
#pragma unroll
        for (int off = 1; off < 64; off <<= 1) {
            int u = __shfl_up(sc, off, 64);
            if (t >= off) sc += u;
        }
        sstart[t] = sc - v;
        pre[t] = sc - v;
    }
    __syncthreads();
    for (int i = t; i < m; i += 256) {
        uint p = eb[i];
        int low = (int)(p & 127u);
        if ((low >> 6) == half) {
            int pos = atomicAdd(&pre[low & 63], 1);
            if (pos < 2048) colL[pos] = (int)(p >> BSH);
        }
    }
    __syncthreads();
}

// ---- stage one 64-k half of W (f32 [k][n]) into Bs[n][kk] bf16 ----
__device__ inline void stage_w_half(ushort* Bs, const float* __restrict__ W, int h, int t) {
#pragma unroll
    for (int i = 0; i < 8; i++) {
        int idx = t + i * 256;   // 0..2047
        int k4 = idx >> 7;       // 0..15
        int n = idx & 127;
        ushort o[4];
#pragma unroll
        for (int j = 0; j < 4; j++) o[j] = f2bf(W[(h * 64 + k4 * 4 + j) * NFEAT + n]);
        uint2 pk;
        __builtin_memcpy(&pk, o, 8);
        *(uint2*)&Bs[n * HP + k4 * 4] = pk;
    }
}

// ---------------- degree histogram (global atomics, int4 reads) ----------------
__global__ __launch_bounds__(256) void k_deg(const int* __restrict__ dst,
                                             int* __restrict__ deg, int E) {
    int i = blockIdx.x * 256 + threadIdx.x;
    int stride = gridDim.x * 256;
    int E4 = E >> 2;
    const int4* d4 = (const int4*)dst;
    for (int k = i; k < E4; k += stride) {
        int4 v = d4[k];
        atomicAdd(&deg[v.x], 1);
        atomicAdd(&deg[v.y], 1);
        atomicAdd(&deg[v.z], 1);
        atomicAdd(&deg[v.w], 1);
    }
    for (int k = E4 * 4 + i; k < E; k += stride) atomicAdd(&deg[dst[k]], 1);
}

// ---------------- bsort body: LDS counting sort per 2048-edge chunk ----------------
__device__ inline void bsort_body(char* smem, int sid,
                                  const int* __restrict__ src,
                                  const int* __restrict__ dst,
                                  int* __restrict__ gcnt,
                                  uint* __restrict__ ebuf, int E, int NB) {
    int* cnt_ = (int*)smem;                 // 1024
    int* loff = cnt_ + MAXNB;               // 1024
    int* gbase = loff + MAXNB;              // 1024
    int* wpart = gbase + MAXNB;             // 4
    uint* sv = (uint*)(wpart + 4);          // 2048
    ushort* sb = (ushort*)(sv + CH2);       // 2048

    int t = threadIdx.x;
    int e0 = sid * CH2;
    int m = min(CH2, E - e0);

#pragma unroll
    for (int i = t; i < MAXNB; i += 256) cnt_[i] = 0;
    __syncthreads();
    for (int e = e0 + t; e < e0 + m; e += 256) atomicAdd(&cnt_[dst[e] >> BSH], 1);
    __syncthreads();
    for (int b = t; b < NB; b += 256) {
        int c = cnt_[b];
        gbase[b] = c ? (b * BCAP + atomicAdd(&gcnt[b], c)) : 0;
    }
    int v0 = cnt_[t * 4], v1 = cnt_[t * 4 + 1], v2 = cnt_[t * 4 + 2], v3 = cnt_[t * 4 + 3];
    int my = v0 + v1 + v2 + v3;
    int lane = t & 63, wv = t >> 6;
    int sc = my;
#pragma unroll
    for (int off = 1; off < 64; off <<= 1) {
        int up = __shfl_up(sc, off, 64);
        if (lane >= off) sc += up;
    }
    if (lane == 63) wpart[wv] = sc;
    __syncthreads();
    int wbase = 0;
    for (int j = 0; j < wv; j++) wbase += wpart[j];
    int run = wbase + sc - my;
    loff[t * 4] = run; cnt_[t * 4] = run; run += v0;
    loff[t * 4 + 1] = run; cnt_[t * 4 + 1] = run; run += v1;
    loff[t * 4 + 2] = run; cnt_[t * 4 + 2] = run; run += v2;
    loff[t * 4 + 3] = run; cnt_[t * 4 + 3] = run;
    __syncthreads();
    for (int e = e0 + t; e < e0 + m; e += 256) {
        int d = dst[e];
        int b = d >> BSH;
        int p = atomicAdd(&cnt_[b], 1);
        sv[p] = ((uint)src[e] << BSH) | (uint)(d & ((1 << BSH) - 1));  // N < 2^17
        sb[p] = (ushort)b;
    }
    __syncthreads();
    for (int i = t; i < m; i += 256) {
        int b = sb[i];
        int slot = gbase[b] + (i - loff[b]);
        if (slot < (b + 1) * BCAP) ebuf[slot] = sv[i];
    }
}

// ---------------- gemm1 body: hs'[m][n] = bf16( dinv_m * sum_k x[m][k] W[k][n] ) ----
__device__ inline void gemm_body_f32(ushort* Bs, int bid, const float* __restrict__ Ap,
                                     const float* __restrict__ W,
                                     const int* __restrict__ deg,
                                     ushort* __restrict__ hs, int M) {
    int t = threadIdx.x;
    int w = t >> 6, l = t & 63;
    int q = l >> 4, ln = l & 15;
    int row0 = (bid * 4 + w) * 16;

    int arow = row0 + ln;
    if (arow >= M) arow = M - 1;
    s8v afr[4];
    const float* A = Ap + (size_t)arow * NFEAT + q * 8;
#pragma unroll
    for (int g = 0; g < 4; g++) {
        float4 f0 = *(const float4*)(A + g * 32);
        float4 f1 = *(const float4*)(A + g * 32 + 4);
        ushort o[8] = {f2bf(f0.x), f2bf(f0.y), f2bf(f0.z), f2bf(f0.w),
                       f2bf(f1.x), f2bf(f1.y), f2bf(f1.z), f2bf(f1.w)};
        __builtin_memcpy(&afr[g], o, 16);
    }

    f4v acc[8];
#pragma unroll
    for (int nt = 0; nt < 8; nt++) acc[nt] = (f4v){0.f, 0.f, 0.f, 0.f};

#pragma unroll
    for (int h = 0; h < 2; h++) {
        if (h) __syncthreads();
        stage_w_half(Bs, W, h, t);
        __syncthreads();
#pragma unroll
        for (int nt = 0; nt < 8; nt++) {
            const ushort* Bp = Bs + (nt * 16 + ln) * HP + q * 8;
#pragma unroll
            for (int ks = 0; ks < 2; ks++) {
                s8v bfr = *(const s8v*)(Bp + ks * 32);
                acc[nt] = __builtin_amdgcn_mfma_f32_16x16x32_bf16(afr[h * 2 + ks], bfr, acc[nt], 0, 0, 0);
            }
        }
    }

#pragma unroll
    for (int r = 0; r < 4; r++) {
        int row = row0 + q * 4 + r;
        if (row < M) {
            float sc = rsqrtf((float)(deg[row] + 1));
            ushort* hp = hs + (size_t)row * NFEAT + ln;
#pragma unroll
            for (int nt = 0; nt < 8; nt++) hp[nt * 16] = f2bf(acc[nt][r] * sc);
        }
    }
}

// ---------------- fused: bsort (1/3 of blocks) + gemm1 (2/3) ----------------
__global__ __launch_bounds__(256) void k_fusedA(const int* __restrict__ src,
                                                const int* __restrict__ dst,
                                                int* __restrict__ gcnt,
                                                uint* __restrict__ ebuf,
                                                int E, int NB, int chBlk,
                                                const float* __restrict__ x,
                                                const float* __restrict__ W1,
                                                const int* __restrict__ deg,
                                                ushort* __restrict__ hs, int M) {
    __shared__ __align__(16) char smem[24592];  // bsort 24592 | gemm Bs 18432
    int bid = blockIdx.x;
    int sid = bid / 3, r = bid % 3;
    if (r == 0 && sid < chBlk) {
        bsort_body(smem, sid, src, dst, gcnt, ebuf, E, NB);
    } else {
        int sorts_before = min(sid + (r ? 1 : 0), chBlk);
        gemm_body_f32((ushort*)smem, bid - sorts_before, x, W1, deg, hs, M);
    }
}

// ---------------- aggB1: half-bucket sort + gather(hs1') + gemm2 -> hs2' ------
__global__ __launch_bounds__(256, 4) void k_aggB1(const uint4* __restrict__ hs4,
                                                  const uint* __restrict__ ebuf,
                                                  const int* __restrict__ gcnt,
                                                  const float* __restrict__ bias,
                                                  const float* __restrict__ W2,
                                                  ushort* __restrict__ hs2, int N) {
    __shared__ __align__(16) char smem[36096];
    ushort* yT = (ushort*)smem;                 // 64*132*2 = 16896
    char* scr = smem + 16896;                   // 18432: colL | Bs
    int* cnt = (int*)(smem + 35328);            // 64
    int* sstart = (int*)(smem + 35584);         // 64
    int* pre = (int*)(smem + 35840);            // 64
    int* colL = (int*)scr;                      // 2064 ints
    ushort* Bs = (ushort*)scr;

    int t = threadIdx.x;
    int b = blockIdx.x >> 1, half = blockIdx.x & 1;
    int base = (b << BSH) + half * 64;

    half_sort(ebuf, gcnt, b, half, cnt, sstart, pre, colL);

    int grp = t >> 4, sub = t & 15;
    const float4* b4 = (const float4*)bias;
    float4 bb0 = b4[sub * 2], bb1 = b4[sub * 2 + 1];

    // ---- phase A: gather + y = relu(dinv*sum + b1) -> yT
    for (int i = 0; i < 4; i++) {
        int lo = grp + i * 16;           // local node 0..63
        int node = base + lo;
        uint4 pk = make_uint4(0, 0, 0, 0);
        if (node < N) {
            f2v a[4];
#pragma unroll
            for (int j = 0; j < 4; j++) a[j] = (f2v){0.f, 0.f};
            int s = sstart[lo];
            int e = min(s + cnt[lo], 2048);
            node_gather_lds(hs4, colL, s, e, node, sub, a);
            float di = rsqrtf((float)(cnt[lo] + 1));
            ushort o[8];
            o[0] = f2bf(fmaxf(fmaf(di, a[0].x, bb0.x), 0.f));
            o[1] = f2bf(fmaxf(fmaf(di, a[0].y, bb0.y), 0.f));
            o[2] = f2bf(fmaxf(fmaf(di, a[1].x, bb0.z), 0.f));
            o[3] = f2bf(fmaxf(fmaf(di, a[1].y, bb0.w), 0.f));
            o[4] = f2bf(fmaxf(fmaf(di, a[2].x, bb1.x), 0.f));
            o[5] = f2bf(fmaxf(fmaf(di, a[2].y, bb1.y), 0.f));
            o[6] = f2bf(fmaxf(fmaf(di, a[3].x, bb1.z), 0.f));
            o[7] = f2bf(fmaxf(fmaf(di, a[3].y, bb1.w), 0.f));
            __builtin_memcpy(&pk, o, 16);
        }
        *(uint4*)&yT[lo * YP + sub * 8] = pk;
    }
    __syncthreads();  // yT complete; colL reads done -> scr reusable as Bs

    // ---- phase B: hs2'[64 x 128] = dinv * (yT @ W2)
    int w = t >> 6, l = t & 63;
    int q = l >> 4, ln = l & 15;
    s8v a2[4];
#pragma unroll
    for (int g = 0; g < 4; g++)
        a2[g] = *(const s8v*)&yT[(w * 16 + ln) * YP + g * 32 + q * 8];

    f4v acc[8];
#pragma unroll
    for (int nt = 0; nt < 8; nt++) acc[nt] = (f4v){0.f, 0.f, 0.f, 0.f};
#pragma unroll
    for (int h = 0; h < 2; h++) {
        if (h) __syncthreads();
        stage_w_half(Bs, W2, h, t);
        __syncthreads();
#pragma unroll
        for (int nt = 0; nt < 8; nt++) {
            const ushort* Bp = Bs + (nt * 16 + ln) * HP + q * 8;
#pragma unroll
            for (int ks = 0; ks < 2; ks++) {
                s8v bfr = *(const s8v*)(Bp + ks * 32);
                acc[nt] = __builtin_amdgcn_mfma_f32_16x16x32_bf16(a2[h * 2 + ks], bfr, acc[nt], 0, 0, 0);
            }
        }
    }
#pragma unroll
    for (int rr = 0; rr < 4; rr++) {
        int lrow = w * 16 + q * 4 + rr;
        int node = base + lrow;
        if (node < N) {
            float sc = rsqrtf((float)(cnt[lrow] + 1));
            ushort* hp = hs2 + (size_t)node * NFEAT + ln;
#pragma unroll
            for (int nt = 0; nt < 8; nt++) hp[nt * 16] = f2bf(acc[nt][rr] * sc);
        }
    }
}

// ---------------- aggB2: half-bucket sort + gather(hs2') -> out (f32) ----------
__global__ __launch_bounds__(256, 6) void k_aggB2(const uint4* __restrict__ hs4,
                                                  const uint* __restrict__ ebuf,
                                                  const int* __restrict__ gcnt,
                                                  const float* __restrict__ bias,
                                                  float* __restrict__ outp, int N) {
    __shared__ int cnt[64];
    __shared__ int sstart[64];
    __shared__ int pre[64];
    __shared__ int colL[CLCAP];

    int t = threadIdx.x;
    int b = blockIdx.x >> 1, half = blockIdx.x & 1;
    int base = (b << BSH) + half * 64;

    half_sort(ebuf, gcnt, b, half, cnt, sstart, pre, colL);

    int grp = t >> 4, sub = t & 15;
    const float4* b4 = (const float4*)bias;
    float4 bb0 = b4[sub * 2], bb1 = b4[sub * 2 + 1];

    for (int i = 0; i < 4; i++) {
        int lo = grp + i * 16;
        int node = base + lo;
        if (node >= N) continue;  // no barriers below
        f2v a[4];
#pragma unroll
        for (int j = 0; j < 4; j++) a[j] = (f2v){0.f, 0.f};
        int s = sstart[lo];
        int e = min(s + cnt[lo], 2048);
        node_gather_lds(hs4, colL, s, e, node, sub, a);
        float di = rsqrtf((float)(cnt[lo] + 1));
        float r[8];
        r[0] = fmaxf(fmaf(di, a[0].x, bb0.x), 0.f);
        r[1] = fmaxf(fmaf(di, a[0].y, bb0.y), 0.f);
        r[2] = fmaxf(fmaf(di, a[1].x, bb0.z), 0.f);
        r[3] = fmaxf(fmaf(di, a[1].y, bb0.w), 0.f);
        r[4] = fmaxf(fmaf(di, a[2].x, bb1.x), 0.f);
        r[5] = fmaxf(fmaf(di, a[2].y, bb1.y), 0.f);
        r[6] = fmaxf(fmaf(di, a[3].x, bb1.z), 0.f);
        r[7] = fmaxf(fmaf(di, a[3].y, bb1.w), 0.f);
        float* orow = outp + (size_t)node * NFEAT + sub * 8;
        f4v r0 = {r[0], r[1], r[2], r[3]};
        f4v r1 = {r[4], r[5], r[6], r[7]};
        __builtin_nontemporal_store(r0, (f4v*)orow);
        __builtin_nontemporal_store(r1, (f4v*)(orow + 4));
    }
}

// ---------------- launch ----------------
extern "C" void kernel_launch(void* const* d_in, const int* in_sizes, int n_in,
                              void* d_out, int out_size, void* d_ws, size_t ws_size,
                              hipStream_t stream) {
    const float* x = (const float*)d_in[0];
    const int* ei = (const int*)d_in[1];
    const float* W1 = (const float*)d_in[2];
    const float* b1 = (const float*)d_in[3];
    const float* W2 = (const float*)d_in[4];
    const float* b2 = (const float*)d_in[5];
    float* out = (float*)d_out;

    const int N = in_sizes[0] / NFEAT;  // 100000  (< 2^17 for 4B edge pack)
    const int E = in_sizes[1] / 2;      // 1600000
    const int* src = ei;
    const int* dst = ei + E;
    const int NB = (N + (1 << BSH) - 1) >> BSH;  // 782

    char* w = (char*)d_ws;
    size_t off = 0;
    auto alloc = [&](size_t bytes) -> void* {
        void* p = w + off;
        off = (off + bytes + 511) & ~(size_t)511;
        return p;
    };
    ushort* hs = (ushort*)alloc((size_t)N * NFEAT * 2);
    ushort* hs2 = (ushort*)alloc((size_t)N * NFEAT * 2);
    int* deg = (int*)alloc((size_t)N * 4);
    uint* ebuf = (uint*)alloc((size_t)NB * BCAP * 4);  // 12.8 MB
    int* gcnt = (int*)alloc((size_t)MAXNB * 4);
    (void)ws_size; (void)n_in; (void)out_size;

    const int sortBlk = (E + CH2 - 1) / CH2;      // 782 sort chunks
    const int gemmBlk = (N + 63) / 64;            // 1563 gemm tiles
    const int aggBlk = 2 * NB;                    // 1564 half-bucket blocks

    hipMemsetAsync(deg, 0, (size_t)N * 4, stream);
    hipMemsetAsync(gcnt, 0, (size_t)MAXNB * 4, stream);
    k_deg<<<1024, 256, 0, stream>>>(dst, deg, E);
    // bsort (1/3) || gemm1 with dinv epilogue (2/3)
    k_fusedA<<<sortBlk + gemmBlk, 256, 0, stream>>>(src, dst, gcnt, ebuf, E, NB, sortBlk,
                                                    x, W1, deg, hs, N);
    k_aggB1<<<aggBlk, 256, 0, stream>>>((const uint4*)hs, ebuf, gcnt, b1, W2, hs2, N);
    k_aggB2<<<aggBlk, 256, 0, stream>>>((const uint4*)hs2, ebuf, gcnt, b2, out, N);
}

// Round 9
// 293.556 us; speedup vs baseline: 1.2191x; 1.2191x over previous
//
#include <hip/hip_runtime.h>

// GCN 2-layer: h = relu(Ahat @ (x @ W) + b), twice.
// Round 17: revert to R6 structure (best measured: bsort -> fill2||gemm1 ->
// aggG -> agg2) with R7's proven aggG launch_bounds(256,4). New: k_bsort
// rebuilt at CH2=8192 / 512 threads -> 196 chunks instead of 782: 3x fewer
// device-scope gcnt reservation atomics (485K->153K RMWs on 49 lines, the
// suspected hidden ~75us) and 4x amortization of the per-chunk histogram/
// scan/barrier overhead. LDS 60KB -> 2 blocks/CU x 8 waves = full 16 waves.

#define NFEAT 128
#define BSH 7                  // 128 nodes per bucket
#define MAXNB 1024             // >= NB = ceil(N/128) = 782
#define BCAP 4096              // per-bucket ebuf capacity (mean 2046, sigma 45)
#define HP 72                  // ushorts per Bs row (64 k + 8 pad); word-stride 36 == 4 mod 32
#define YP 132                 // ushorts per yT row (128 + 4)
#define CH2 8192               // edges per bsort chunk (512 threads)

typedef __attribute__((ext_vector_type(8))) short s8v;  // 8 bf16 MFMA A/B frag
typedef __attribute__((ext_vector_type(4))) float f4v;  // MFMA C/D frag
typedef __attribute__((ext_vector_type(2))) float f2v;  // packed f32 pair
typedef __attribute__((ext_vector_type(4))) uint u4v;   // NT-store vector

// ---- bf16 helpers (rne) ----
__device__ inline ushort f2bf(float f) {
    union { float f; uint u; } x; x.f = f;
    uint u = x.u;
    return (ushort)((u + 0x7fffu + ((u >> 16) & 1u)) >> 16);
}
__device__ inline f2v unpk(uint u) {
    union { uint u; float f; } lo, hi;
    lo.u = u << 16;
    hi.u = u & 0xffff0000u;
    return (f2v){lo.f, hi.f};
}
__device__ inline void upfma2(uint4 v, float g, f2v* a) {
    a[0] += g * unpk(v.x);
    a[1] += g * unpk(v.y);
    a[2] += g * unpk(v.z);
    a[3] += g * unpk(v.w);
}

// ---- per-node gather: a[4] += dinv-weighted neighbor rows (4-deep pipeline) ----
__device__ inline void node_gather(const uint4* __restrict__ hs4,
                                   const int* __restrict__ row_ptr,
                                   const int* __restrict__ col,
                                   const float* __restrict__ dinv,
                                   int node, int sub, f2v* a) {
    uint4 vself = hs4[(size_t)node * 16 + sub];
    float dself = dinv[node];
    int s = row_ptr[node], e = row_ptr[node + 1];
    int nb = (e - s) >> 2;
    int k = s;
    if (nb > 0) {
        int c0 = col[k], c1 = col[k + 1], c2 = col[k + 2], c3 = col[k + 3];
        uint4 v0 = hs4[(size_t)c0 * 16 + sub];
        uint4 v1 = hs4[(size_t)c1 * 16 + sub];
        uint4 v2 = hs4[(size_t)c2 * 16 + sub];
        uint4 v3 = hs4[(size_t)c3 * 16 + sub];
        float g0 = dinv[c0], g1 = dinv[c1], g2 = dinv[c2], g3 = dinv[c3];
        int d0 = col[k + 4], d1 = col[k + 5], d2 = col[k + 6], d3 = col[k + 7];
        k += 8;
        upfma2(vself, dself, a);  // self-loop FIRST (order preserved)
        for (int it = 1; it < nb; ++it, k += 4) {
            uint4 w0 = hs4[(size_t)d0 * 16 + sub];
            uint4 w1 = hs4[(size_t)d1 * 16 + sub];
            uint4 w2 = hs4[(size_t)d2 * 16 + sub];
            uint4 w3 = hs4[(size_t)d3 * 16 + sub];
            float h0 = dinv[d0], h1 = dinv[d1], h2 = dinv[d2], h3 = dinv[d3];
            int t0 = col[k], t1 = col[k + 1], t2 = col[k + 2], t3 = col[k + 3];
            upfma2(v0, g0, a); upfma2(v1, g1, a); upfma2(v2, g2, a); upfma2(v3, g3, a);
            v0 = w0; v1 = w1; v2 = w2; v3 = w3;
            g0 = h0; g1 = h1; g2 = h2; g3 = h3;
            d0 = t0; d1 = t1; d2 = t2; d3 = t3;
        }
        upfma2(v0, g0, a); upfma2(v1, g1, a); upfma2(v2, g2, a); upfma2(v3, g3, a);
        k = s + nb * 4;
    } else {
        upfma2(vself, dself, a);
    }
    for (; k < e; ++k) {
        int c = col[k];
        upfma2(hs4[(size_t)c * 16 + sub], dinv[c], a);
    }
}

// ---- stage one 64-k half of W (f32 [k][n]) into Bs[n][kk] bf16 (256 threads) ----
__device__ inline void stage_w_half(ushort* Bs, const float* __restrict__ W, int h, int t) {
#pragma unroll
    for (int i = 0; i < 8; i++) {
        int idx = t + i * 256;   // 0..2047
        int k4 = idx >> 7;       // 0..15
        int n = idx & 127;
        ushort o[4];
#pragma unroll
        for (int j = 0; j < 4; j++) o[j] = f2bf(W[(h * 64 + k4 * 4 + j) * NFEAT + n]);
        uint2 pk;
        __builtin_memcpy(&pk, o, 8);
        *(uint2*)&Bs[n * HP + k4 * 4] = pk;
    }
}

// ---------------- bucket sort scatter: 512 threads, 8192-edge chunks ----------------
// Histogram over 128-node buckets -> ONE global reservation round per chunk ->
// shfl scan (2 buckets/thread, 8 wave partials) -> LDS scatter -> burst write.
__global__ __launch_bounds__(512) void k_bsort(const int* __restrict__ src,
                                               const int* __restrict__ dst,
                                               int* __restrict__ gcnt,
                                               uint* __restrict__ ebuf,
                                               int E, int NB) {
    __shared__ int cnt_[MAXNB];   // histogram -> running scatter counter
    __shared__ int loff[MAXNB];   // local exclusive offset per bucket
    __shared__ int gbase[MAXNB];  // global run base per bucket
    __shared__ int wpart[8];
    __shared__ uint sv[CH2];      // sorted packed edges (32 KB)
    __shared__ ushort sb[CH2];    // bucket id per sorted slot (16 KB)

    int t = threadIdx.x;
    int e0 = blockIdx.x * CH2;
    int m = min(CH2, E - e0);

#pragma unroll
    for (int i = t; i < MAXNB; i += 512) cnt_[i] = 0;
    __syncthreads();
    for (int e = e0 + t; e < e0 + m; e += 512) atomicAdd(&cnt_[dst[e] >> BSH], 1);
    __syncthreads();
    // reserve global runs (one atomic per nonzero bucket per chunk)
    for (int b = t; b < NB; b += 512) {
        int c = cnt_[b];
        gbase[b] = c ? (b * BCAP + atomicAdd(&gcnt[b], c)) : 0;
    }
    // exclusive scan over 1024 buckets: 2/thread + shfl wave scan + 8 partials
    int v0 = cnt_[t * 2], v1 = cnt_[t * 2 + 1];
    int my = v0 + v1;
    int lane = t & 63, wv = t >> 6;
    int sc = my;
#pragma unroll
    for (int off = 1; off < 64; off <<= 1) {
        int up = __shfl_up(sc, off, 64);
        if (lane >= off) sc += up;
    }
    if (lane == 63) wpart[wv] = sc;
    __syncthreads();  // wpart + gbase visible; all cnt_ reads done
    int wbase = 0;
#pragma unroll
    for (int j = 0; j < 8; j++) wbase += (j < wv) ? wpart[j] : 0;
    int run = wbase + sc - my;  // exclusive prefix over threads
    loff[t * 2] = run; cnt_[t * 2] = run; run += v0;
    loff[t * 2 + 1] = run; cnt_[t * 2 + 1] = run;
    __syncthreads();
    // LDS scatter to sorted order
    for (int e = e0 + t; e < e0 + m; e += 512) {
        int d = dst[e];
        int b = d >> BSH;
        int p = atomicAdd(&cnt_[b], 1);
        sv[p] = ((uint)src[e] << BSH) | (uint)(d & ((1 << BSH) - 1));  // N < 2^17
        sb[p] = (ushort)b;
    }
    __syncthreads();
    // burst write-out: consecutive i -> consecutive global within each run
    for (int i = t; i < m; i += 512) {
        int b = sb[i];
        int slot = gbase[b] + (i - loff[b]);
        if (slot < (b + 1) * BCAP) ebuf[slot] = sv[i];
    }
}

// ---------------- GEMM body: hs[m][n] = bf16( sum_k A[m][k] W[k][n] ) ----------
// 4 waves x 16 rows per block; W staged in two 64-k halves (18.4 KB LDS).
template <bool ABF16>
__device__ inline void gemm_body(ushort* Bs, int bid, const void* __restrict__ Ap,
                                 const float* __restrict__ W,
                                 ushort* __restrict__ hs, int M) {
    int t = threadIdx.x;
    int w = t >> 6, l = t & 63;
    int q = l >> 4, ln = l & 15;
    int row0 = (bid * 4 + w) * 16;

    int arow = row0 + ln;
    if (arow >= M) arow = M - 1;
    s8v afr[4];
    if (ABF16) {
        const ushort* A = (const ushort*)Ap + (size_t)arow * NFEAT + q * 8;
#pragma unroll
        for (int g = 0; g < 4; g++) afr[g] = *(const s8v*)(A + g * 32);
    } else {
        const float* A = (const float*)Ap + (size_t)arow * NFEAT + q * 8;
#pragma unroll
        for (int g = 0; g < 4; g++) {
            float4 f0 = *(const float4*)(A + g * 32);
            float4 f1 = *(const float4*)(A + g * 32 + 4);
            ushort o[8] = {f2bf(f0.x), f2bf(f0.y), f2bf(f0.z), f2bf(f0.w),
                           f2bf(f1.x), f2bf(f1.y), f2bf(f1.z), f2bf(f1.w)};
            __builtin_memcpy(&afr[g], o, 16);
        }
    }

    f4v acc[8];
#pragma unroll
    for (int nt = 0; nt < 8; nt++) acc[nt] = (f4v){0.f, 0.f, 0.f, 0.f};

#pragma unroll
    for (int h = 0; h < 2; h++) {
        if (h) __syncthreads();
        stage_w_half(Bs, W, h, t);
        __syncthreads();
#pragma unroll
        for (int nt = 0; nt < 8; nt++) {
            const ushort* Bp = Bs + (nt * 16 + ln) * HP + q * 8;
#pragma unroll
            for (int ks = 0; ks < 2; ks++) {
                s8v bfr = *(const s8v*)(Bp + ks * 32);
                acc[nt] = __builtin_amdgcn_mfma_f32_16x16x32_bf16(afr[h * 2 + ks], bfr, acc[nt], 0, 0, 0);
            }
        }
    }

#pragma unroll
    for (int r = 0; r < 4; r++) {
        int row = row0 + q * 4 + r;
        if (row < M) {
            ushort* hp = hs + (size_t)row * NFEAT + ln;
#pragma unroll
            for (int nt = 0; nt < 8; nt++) hp[nt * 16] = f2bf(acc[nt][r]);
        }
    }
}

// ---------------- fill2 body: per-bucket CSR finalize ----------------
__device__ inline void fill2_body(char* smem, int b,
                                  const uint* __restrict__ ebuf,
                                  const int* __restrict__ gcnt,
                                  int* __restrict__ row_ptr,
                                  float* __restrict__ dinv,
                                  int* __restrict__ col,
                                  int N, int E, int NB) {
    int* cnt = (int*)smem;            // 128
    int* pre = cnt + 128;             // 128
    int* sred = pre + 128;            // 256 (only 4 used)
    int* colL = sred + 256;           // 4096   total 4608 ints = 18432 B
    int t = threadIdx.x;
    int part = 0;
    for (int j = t; j < b; j += 256) part += gcnt[j];
#pragma unroll
    for (int off = 32; off >= 1; off >>= 1) part += __shfl_down(part, off, 64);
    if ((t & 63) == 0) sred[t >> 6] = part;
    __syncthreads();
    int gb = sred[0] + sred[1] + sred[2] + sred[3];
    int m = min(gcnt[b], BCAP);
    if (t < 128) cnt[t] = 0;
    __syncthreads();
    const uint* eb = ebuf + (size_t)b * BCAP;
    for (int i = t; i < m; i += 256) atomicAdd(&cnt[eb[i] & 127], 1);
    __syncthreads();
    if (t < 128) pre[t] = cnt[t];
    __syncthreads();
    for (int off = 1; off < 128; off <<= 1) {
        int add = (t >= off && t < 128) ? pre[t - off] : 0;
        __syncthreads();
        if (t < 128) pre[t] += add;
        __syncthreads();
    }
    if (t < 128) {
        pre[t] -= cnt[t];
        int node = (b << BSH) + t;
        if (node < N) {
            row_ptr[node] = gb + pre[t];
            dinv[node] = rsqrtf((float)(cnt[t] + 1));
        }
    }
    __syncthreads();
    for (int i = t; i < m; i += 256) {
        uint p = eb[i];
        int pos = atomicAdd(&pre[p & 127], 1);
        colL[pos] = (int)(p >> BSH);
    }
    __syncthreads();
    for (int i = t; i < m; i += 256) col[gb + i] = colL[i];  // coalesced
    if (b == NB - 1 && t == 0) row_ptr[N] = E;
}

// ---------------- fused: fill2 (1/3 of blocks) + gemm1 (2/3) ----------------
__global__ __launch_bounds__(256) void k_fused2(const uint* __restrict__ ebuf,
                                                const int* __restrict__ gcnt,
                                                int* __restrict__ row_ptr,
                                                float* __restrict__ dinv,
                                                int* __restrict__ col,
                                                int N, int E, int NB,
                                                const float* __restrict__ x,
                                                const float* __restrict__ W1,
                                                ushort* __restrict__ hs) {
    __shared__ __align__(16) char smem[18432];  // fill2 arrays OR gemm Bs
    int bid = blockIdx.x;
    int r = bid % 3;
    int fid = bid / 3;
    if (r == 0 && fid < NB) {
        fill2_body(smem, fid, ebuf, gcnt, row_ptr, dinv, col, N, E, NB);
    } else {
        int fills_before = min(fid + (r ? 1 : 0), NB);
        gemm_body<false>((ushort*)smem, bid - fills_before, x, W1, hs, N);
    }
}

// ---------------- fused aggregate(layer1) + gemm2, LDS reused yT->Bs ----------
__global__ __launch_bounds__(256, 4) void k_aggG(const uint4* __restrict__ hs4,
                                                 const int* __restrict__ row_ptr,
                                                 const int* __restrict__ col,
                                                 const float* __restrict__ dinv,
                                                 const float* __restrict__ bias,
                                                 const float* __restrict__ W2,
                                                 ushort* __restrict__ hs2, int N) {
    __shared__ __align__(16) ushort smem[128 * HP];  // 18432 B: yT (16896) then Bs
    ushort* yT = smem;
    ushort* Bs = smem;
    int t = threadIdx.x;
    int grp = t >> 4, sub = t & 15;
    int base = blockIdx.x * 64;

    const float4* b4 = (const float4*)bias;
    float4 bb0 = b4[sub * 2], bb1 = b4[sub * 2 + 1];

    // ---- phase A: gather + y = relu(dinv*acc + b), park in yT
    for (int i = 0; i < 4; i++) {
        int myn = grp + i * 16;
        int node = base + myn;
        uint4 pk = make_uint4(0, 0, 0, 0);
        if (node < N) {
            f2v a[4];
#pragma unroll
            for (int j = 0; j < 4; j++) a[j] = (f2v){0.f, 0.f};
            node_gather(hs4, row_ptr, col, dinv, node, sub, a);
            float di = dinv[node];
            ushort o[8];
            o[0] = f2bf(fmaxf(fmaf(di, a[0].x, bb0.x), 0.f));
            o[1] = f2bf(fmaxf(fmaf(di, a[0].y, bb0.y), 0.f));
            o[2] = f2bf(fmaxf(fmaf(di, a[1].x, bb0.z), 0.f));
            o[3] = f2bf(fmaxf(fmaf(di, a[1].y, bb0.w), 0.f));
            o[4] = f2bf(fmaxf(fmaf(di, a[2].x, bb1.x), 0.f));
            o[5] = f2bf(fmaxf(fmaf(di, a[2].y, bb1.y), 0.f));
            o[6] = f2bf(fmaxf(fmaf(di, a[3].x, bb1.z), 0.f));
            o[7] = f2bf(fmaxf(fmaf(di, a[3].y, bb1.w), 0.f));
            __builtin_memcpy(&pk, o, 16);
        }
        *(uint4*)&yT[myn * YP + sub * 8] = pk;
    }
    __syncthreads();

    // ---- hoist A-fragments to registers, then free yT for Bs
    int w = t >> 6, l = t & 63;
    int q = l >> 4, ln = l & 15;
    s8v a2[4];
#pragma unroll
    for (int g = 0; g < 4; g++)
        a2[g] = *(const s8v*)&yT[(w * 16 + ln) * YP + g * 32 + q * 8];
    __syncthreads();  // all reads of yT done before overwrite

    // ---- phase B: hs2[64 x 128] = yT @ W2 (Bs aliases yT storage)
    f4v acc[8];
#pragma unroll
    for (int nt = 0; nt < 8; nt++) acc[nt] = (f4v){0.f, 0.f, 0.f, 0.f};
#pragma unroll
    for (int h = 0; h < 2; h++) {
        if (h) __syncthreads();  // all waves done reading Bs half h-1
        stage_w_half(Bs, W2, h, t);
        __syncthreads();
#pragma unroll
        for (int nt = 0; nt < 8; nt++) {
            const ushort* Bp = Bs + (nt * 16 + ln) * HP + q * 8;
#pragma unroll
            for (int ks = 0; ks < 2; ks++) {
                s8v bfr = *(const s8v*)(Bp + ks * 32);
                acc[nt] = __builtin_amdgcn_mfma_f32_16x16x32_bf16(a2[h * 2 + ks], bfr, acc[nt], 0, 0, 0);
            }
        }
    }
    // ---- epilogue: store hs2 rows (col = nt*16 + ln, row = w*16 + q*4 + rr)
#pragma unroll
    for (int rr = 0; rr < 4; rr++) {
        int node = base + w * 16 + q * 4 + rr;
        if (node < N) {
            ushort* hp = hs2 + (size_t)node * NFEAT + ln;
#pragma unroll
            for (int nt = 0; nt < 8; nt++) hp[nt * 16] = f2bf(acc[nt][rr]);
        }
    }
}

// ---------------- Aggregation (layer 2, final): f32 output ----------------
__global__ __launch_bounds__(256) void k_aggregate(const uint4* __restrict__ hs4,
                                                   const int* __restrict__ row_ptr,
                                                   const int* __restrict__ col,
                                                   const float* __restrict__ dinv,
                                                   const float* __restrict__ bias,
                                                   float* __restrict__ outp, int N) {
    int node = blockIdx.x * 16 + (threadIdx.x >> 4);
    if (node >= N) return;
    int sub = threadIdx.x & 15;

    f2v a[4];
#pragma unroll
    for (int j = 0; j < 4; j++) a[j] = (f2v){0.f, 0.f};
    node_gather(hs4, row_ptr, col, dinv, node, sub, a);

    float di = dinv[node];
    const float4* b4 = (const float4*)bias;
    float4 b0 = b4[sub * 2], b1 = b4[sub * 2 + 1];
    float r[8];
    r[0] = fmaxf(fmaf(di, a[0].x, b0.x), 0.f);
    r[1] = fmaxf(fmaf(di, a[0].y, b0.y), 0.f);
    r[2] = fmaxf(fmaf(di, a[1].x, b0.z), 0.f);
    r[3] = fmaxf(fmaf(di, a[1].y, b0.w), 0.f);
    r[4] = fmaxf(fmaf(di, a[2].x, b1.x), 0.f);
    r[5] = fmaxf(fmaf(di, a[2].y, b1.y), 0.f);
    r[6] = fmaxf(fmaf(di, a[3].x, b1.z), 0.f);
    r[7] = fmaxf(fmaf(di, a[3].y, b1.w), 0.f);
    float* orow = outp + (size_t)node * NFEAT + sub * 8;
    f4v r0 = {r[0], r[1], r[2], r[3]};
    f4v r1 = {r[4], r[5], r[6], r[7]};
    __builtin_nontemporal_store(r0, (f4v*)orow);
    __builtin_nontemporal_store(r1, (f4v*)(orow + 4));
}

// ---------------- launch ----------------
extern "C" void kernel_launch(void* const* d_in, const int* in_sizes, int n_in,
                              void* d_out, int out_size, void* d_ws, size_t ws_size,
                              hipStream_t stream) {
    const float* x = (const float*)d_in[0];
    const int* ei = (const int*)d_in[1];
    const float* W1 = (const float*)d_in[2];
    const float* b1 = (const float*)d_in[3];
    const float* W2 = (const float*)d_in[4];
    const float* b2 = (const float*)d_in[5];
    float* out = (float*)d_out;

    const int N = in_sizes[0] / NFEAT;  // 100000  (< 2^17 for 4B edge pack)
    const int E = in_sizes[1] / 2;      // 1600000
    const int* src = ei;
    const int* dst = ei + E;
    const int NB = (N + (1 << BSH) - 1) >> BSH;  // 782

    char* w = (char*)d_ws;
    size_t off = 0;
    auto alloc = [&](size_t bytes) -> void* {
        void* p = w + off;
        off = (off + bytes + 511) & ~(size_t)511;
        return p;
    };
    ushort* hs = (ushort*)alloc((size_t)N * NFEAT * 2);
    ushort* hs2 = (ushort*)alloc((size_t)N * NFEAT * 2);
    int* row_ptr = (int*)alloc((size_t)(N + 1) * 4);
    float* dinv = (float*)alloc((size_t)N * 4);
    int* col = (int*)alloc((size_t)(E + 64) * 4);   // +64: gather prefetch over-read pad
    uint* ebuf = (uint*)alloc((size_t)NB * BCAP * 4);  // 12.8 MB
    int* gcnt = (int*)alloc((size_t)MAXNB * 4);
    (void)ws_size; (void)n_in; (void)out_size;

    const int sortBlk = (E + CH2 - 1) / CH2;      // 196 sort chunks (512 threads)
    const int gemmBlk = (N + 63) / 64;            // 1563 gemm/aggG tiles
    const int aggBlk = (N + 15) / 16;             // 16 nodes per block

    hipMemsetAsync(gcnt, 0, (size_t)MAXNB * 4, stream);
    k_bsort<<<sortBlk, 512, 0, stream>>>(src, dst, gcnt, ebuf, E, NB);
    // fill2 (1/3) || gemm1 (2/3)
    k_fused2<<<NB + gemmBlk, 256, 0, stream>>>(ebuf, gcnt, row_ptr, dinv, col, N, E, NB,
                                               x, W1, hs);
    // fused aggregate(layer1) + gemm2 -> hs2 ; then final aggregate -> out
    k_aggG<<<gemmBlk, 256, 0, stream>>>((const uint4*)hs, row_ptr, col, dinv, b1, W2, hs2, N);
    k_aggregate<<<aggBlk, 256, 0, stream>>>((const uint4*)hs2, row_ptr, col, dinv, b2, out, N);
}